// Round 4
// baseline (740.460 us; speedup 1.0000x reference)
//
#include <hip/hip_runtime.h>
#include <cstdint>
#include <cstddef>

using u16 = unsigned short;
typedef short short8 __attribute__((ext_vector_type(8)));
typedef unsigned short us8 __attribute__((ext_vector_type(8)));
typedef unsigned short us4 __attribute__((ext_vector_type(4)));
typedef float f32x4 __attribute__((ext_vector_type(4)));
typedef float f4 __attribute__((ext_vector_type(4)));

#define T_ 1024
#define B_ 8
#define H_ 1024
#define HEADS_ 16
#define HD_ 64
#define N3_ 3072

__device__ __forceinline__ float b2f(u16 u){
  union { float f; unsigned int i; } v; v.i = ((unsigned int)u) << 16; return v.f;
}
__device__ __forceinline__ u16 f2b(float f){
  union { float f; unsigned int i; } v; v.f = f;
  unsigned int r = v.i + 0x7fffu + ((v.i >> 16) & 1u);
  return (u16)(r >> 16);
}

// ---------------- GEMM: C[m,o] = sum_k A[m,k]*W[o,k] ----------------
// A: f32 (or bf16 if A_BF16). W,RA,S,bias: f32. C: bf16 u16 (or f32 if OUT_F32).
// SCALE_A: A row m scaled by RA[m&7,:] (f32 mult). POS_A: A row = pos[m>>3].
// epilogue: optional *S[m&7,o], + bias[o]. 128x128 tile, BK=32, 4 waves, mfma 16x16x32 bf16.
template<bool HAS_S, bool SCALE_A, bool POS_A, bool A_BF16, bool OUT_F32>
__global__ __launch_bounds__(256) void k_gemm(const void* __restrict__ A_, const float* __restrict__ W,
                                              const float* __restrict__ RA, const float* __restrict__ S,
                                              const float* __restrict__ bias, void* __restrict__ C_, int N){
  const int K = 1024;
  const int n0 = blockIdx.x * 128, m0 = blockIdx.y * 128;
  const int tid = threadIdx.x, lane = tid & 63;
  const int wave = tid >> 6, wr = wave >> 1, wc = wave & 1;
  __shared__ alignas(16) u16 At[128 * 32];
  __shared__ alignas(16) u16 Bt[128 * 32];
  f32x4 acc[4][4] = {};

  for (int kt = 0; kt < 32; ++kt){
    const int k0 = kt * 32;
    f4 wv[4];
    us8 avb[2];
    f4 avf[4];
#pragma unroll
    for (int i = 0; i < 4; ++i){
      int c = tid + i * 256, r = c >> 3, sg = c & 7;
      wv[i] = *(const f4*)(W + (size_t)(n0 + r) * K + k0 + sg * 4);
    }
    if (A_BF16){
      const u16* A = (const u16*)A_;
#pragma unroll
      for (int i = 0; i < 2; ++i){
        int c = tid + i * 256, r = c >> 2, sg = c & 3;
        avb[i] = *(const us8*)(A + (size_t)(m0 + r) * K + k0 + sg * 8);
      }
    } else {
      const float* A = (const float*)A_;
#pragma unroll
      for (int i = 0; i < 4; ++i){
        int c = tid + i * 256, r = c >> 3, sg = c & 7;
        int m = m0 + r;
        const float* ap = POS_A ? (A + (size_t)(m >> 3) * K + k0 + sg * 4)
                                : (A + (size_t)m * K + k0 + sg * 4);
        avf[i] = *(const f4*)ap;
        if (SCALE_A){
          f4 rv = *(const f4*)(RA + (m & 7) * K + k0 + sg * 4);
          avf[i] = avf[i] * rv;
        }
      }
    }
    __syncthreads();
#pragma unroll
    for (int i = 0; i < 4; ++i){
      int c = tid + i * 256, r = c >> 3, sg = c & 7;
      us4 pw;
#pragma unroll
      for (int u = 0; u < 4; ++u) pw[u] = f2b(wv[i][u]);
      *(us4*)(Bt + r * 32 + sg * 4) = pw;
    }
    if (A_BF16){
#pragma unroll
      for (int i = 0; i < 2; ++i){
        int c = tid + i * 256, r = c >> 2, sg = c & 3;
        *(us8*)(At + r * 32 + sg * 8) = avb[i];
      }
    } else {
#pragma unroll
      for (int i = 0; i < 4; ++i){
        int c = tid + i * 256, r = c >> 3, sg = c & 7;
        us4 pa;
#pragma unroll
        for (int u = 0; u < 4; ++u) pa[u] = f2b(avf[i][u]);
        *(us4*)(At + r * 32 + sg * 4) = pa;
      }
    }
    __syncthreads();
    short8 af[4], bf[4];
#pragma unroll
    for (int i = 0; i < 4; ++i){
      int ar = wr * 64 + i * 16 + (lane & 15);
      af[i] = *(const short8*)(At + ar * 32 + ((lane >> 4) << 3));
      int br = wc * 64 + i * 16 + (lane & 15);
      bf[i] = *(const short8*)(Bt + br * 32 + ((lane >> 4) << 3));
    }
#pragma unroll
    for (int i = 0; i < 4; ++i)
#pragma unroll
      for (int j = 0; j < 4; ++j)
        acc[i][j] = __builtin_amdgcn_mfma_f32_16x16x32_bf16(af[i], bf[j], acc[i][j], 0, 0, 0);
  }
#pragma unroll
  for (int i = 0; i < 4; ++i){
    int row0 = wr * 64 + i * 16 + ((lane >> 4) << 2);
#pragma unroll
    for (int j = 0; j < 4; ++j){
      int o = n0 + wc * 64 + j * 16 + (lane & 15);
      float bv = bias[o];
#pragma unroll
      for (int jj = 0; jj < 4; ++jj){
        int m = m0 + row0 + jj;
        float v = acc[i][j][jj];
        if (HAS_S) v *= S[(m & 7) * N + o];
        v += bv;
        if (OUT_F32) ((float*)C_)[(size_t)m * N + o] = v;
        else         ((u16*)C_)[(size_t)m * N + o] = f2b(v);
      }
    }
  }
}

// ---------------- fused attention ----------------
// grid (128 n, 32 qb), 512 threads (8 waves). q-tile = 32 rows. ctx (bf16) -> d_out scratch.
__global__ __launch_bounds__(512) void k_attn(const u16* __restrict__ qkv, const u16* __restrict__ rk,
                                              const float* __restrict__ rwb, const float* __restrict__ rrb,
                                              u16* __restrict__ ctx){
  const int n = blockIdx.x, qb = blockIdx.y, q0 = qb * 32;
  const int bat = n >> 4, head = n & 15;
  const int tid = threadIdx.x, lane = tid & 63, wave = tid >> 6;

  __shared__ alignas(16) u16 rwq[32 * 64];
  __shared__ alignas(16) u16 rrq[48 * 64];
  __shared__ alignas(16) u16 gt[1024 * 36];
  __shared__ alignas(16) u16 kvb[128 * 64];
  __shared__ alignas(16) u16 Pt[32 * 64];
  __shared__ alignas(16) float red[128];

  // ---- Phase A: rw_q (32 rows) + rr_q (48 rows, zero past T), bias added, swizzled
#pragma unroll
  for (int rep = 0; rep < 2; ++rep){
    int c = tid + rep * 512;
    if (c < 640){
      int s = c >> 3, sg = c & 7;
      u16* dst; int row; const float* bias;
      if (s < 32){ dst = rwq; row = s; bias = rwb; }
      else       { dst = rrq; row = s - 32; bias = rrb; }
      int qrow = q0 + row;
      float v[8];
      const float* bp2 = bias + head * 64 + sg * 8;
      if (qrow < T_){
        const u16* qp = qkv + ((size_t)qrow * 8 + bat) * N3_ + head * 192 + sg * 8;
        us8 qv = *(const us8*)qp;
        f4 b0 = *(const f4*)bp2, b1 = *(const f4*)(bp2 + 4);
#pragma unroll
        for (int u = 0; u < 4; ++u){ v[u] = b2f(qv[u]) + b0[u]; v[u + 4] = b2f(qv[u + 4]) + b1[u]; }
      } else {
#pragma unroll
        for (int u = 0; u < 8; ++u) v[u] = 0.f;
      }
      us8 pk;
#pragma unroll
      for (int u = 0; u < 8; ++u) pk[u] = f2b(v[u]);
      *(us8*)((char*)dst + row * 128 + ((sg * 16) ^ ((row & 7) << 4))) = pk;
    }
  }

  // ---- Phase B: g[a][r] = rr_q[q0+a] . r_k[r]; store transposed gt[r][a], a<33
  for (int rt = 0; rt < 8; ++rt){
    us8 kv[2];
#pragma unroll
    for (int i = 0; i < 2; ++i){
      int c = tid + i * 512;
      int r = c >> 3, sg = c & 7;
      kv[i] = *(const us8*)(rk + ((size_t)(rt * 128 + r) * 8 + bat) * 1024 + head * 64 + sg * 8);
    }
    __syncthreads();
#pragma unroll
    for (int i = 0; i < 2; ++i){
      int c = tid + i * 512;
      int r = c >> 3, sg = c & 7;
      *(us8*)((char*)kvb + r * 128 + ((sg * 16) ^ ((r & 7) << 4))) = kv[i];
    }
    __syncthreads();
#pragma unroll
    for (int pi = 0; pi < 3; ++pi){
      f32x4 acc = {0.f, 0.f, 0.f, 0.f};
      int arow = pi * 16 + (lane & 15);
      int brow = wave * 16 + (lane & 15);
#pragma unroll
      for (int kk = 0; kk < 2; ++kk){
        int co = kk * 64 + ((lane >> 4) << 4);
        short8 a  = *(const short8*)((const char*)rrq + arow * 128 + (co ^ ((arow & 7) << 4)));
        short8 bv = *(const short8*)((const char*)kvb + brow * 128 + (co ^ ((brow & 7) << 4)));
        acc = __builtin_amdgcn_mfma_f32_16x16x32_bf16(a, bv, acc, 0, 0, 0);
      }
      int rcol = rt * 128 + wave * 16 + (lane & 15);
      int a0 = pi * 16 + ((lane >> 4) << 2);
#pragma unroll
      for (int jj = 0; jj < 4; ++jj){
        int a = a0 + jj;
        if (a < 33) gt[rcol * 36 + a] = f2b(acc[jj]);
      }
    }
  }

  // ---- Phase C: raw scores in registers (fully unrolled -> p[] stays in VGPRs)
  const int wr = wave & 1, wc = wave >> 1;
  float p[16][4];
  float pm[4] = {-3.0e38f, -3.0e38f, -3.0e38f, -3.0e38f};
#pragma unroll
  for (int kt = 0; kt < 16; ++kt){
    int r = tid >> 3, sgc = tid & 7;
    us8 kv = *(const us8*)(qkv + ((size_t)(kt * 64 + r) * 8 + bat) * N3_ + head * 192 + 64 + sgc * 8);
    __syncthreads();
    *(us8*)((char*)kvb + r * 128 + ((sgc * 16) ^ ((r & 7) << 4))) = kv;
    __syncthreads();
    f32x4 acc = {0.f, 0.f, 0.f, 0.f};
    int arow = wr * 16 + (lane & 15);
    int brow = wc * 16 + (lane & 15);
#pragma unroll
    for (int kk = 0; kk < 2; ++kk){
      int co = kk * 64 + ((lane >> 4) << 4);
      short8 a  = *(const short8*)((const char*)rwq + arow * 128 + (co ^ ((arow & 7) << 4)));
      short8 bv = *(const short8*)((const char*)kvb + brow * 128 + (co ^ ((brow & 7) << 4)));
      acc = __builtin_amdgcn_mfma_f32_16x16x32_bf16(a, bv, acc, 0, 0, 0);
    }
    int bcol = kt * 64 + wc * 16 + (lane & 15);
#pragma unroll
    for (int jj = 0; jj < 4; ++jj){
      int aa = wr * 16 + ((lane >> 4) << 2) + jj;
      int a_ = q0 + aa;
      float gv;
      if (bcol <= a_)            gv = b2f(gt[(1023 - a_ + bcol) * 36 + aa]);
      else if (bcol == a_ + 1)   gv = 0.0f;
      else                       gv = b2f(gt[(bcol - a_ - 2) * 36 + aa + 1]);
      float s = (acc[jj] + gv) * 0.125f;
      p[kt][jj] = s;
      pm[jj] = fmaxf(pm[jj], s);
    }
  }

  // ---- softmax (exact two-pass, overflow-proof)
#pragma unroll
  for (int jj = 0; jj < 4; ++jj)
#pragma unroll
    for (int m = 1; m < 16; m <<= 1) pm[jj] = fmaxf(pm[jj], __shfl_xor(pm[jj], m));
  __syncthreads();
  if ((lane & 15) == 0){
#pragma unroll
    for (int jj = 0; jj < 4; ++jj) red[wc * 32 + wr * 16 + ((lane >> 4) << 2) + jj] = pm[jj];
  }
  __syncthreads();
  float M[4];
#pragma unroll
  for (int jj = 0; jj < 4; ++jj){
    int row = wr * 16 + ((lane >> 4) << 2) + jj;
    float m = red[row];
    m = fmaxf(m, red[32 + row]); m = fmaxf(m, red[64 + row]); m = fmaxf(m, red[96 + row]);
    M[jj] = m;
  }
  __syncthreads();
  float L[4] = {0.f, 0.f, 0.f, 0.f};
#pragma unroll
  for (int kt = 0; kt < 16; ++kt)
#pragma unroll
    for (int jj = 0; jj < 4; ++jj){
      float e = __expf(fminf(p[kt][jj] - M[jj], 0.f));
      p[kt][jj] = e;
      L[jj] += e;
    }
#pragma unroll
  for (int jj = 0; jj < 4; ++jj)
#pragma unroll
    for (int m = 1; m < 16; m <<= 1) L[jj] += __shfl_xor(L[jj], m);
  if ((lane & 15) == 0){
#pragma unroll
    for (int jj = 0; jj < 4; ++jj) red[wc * 32 + wr * 16 + ((lane >> 4) << 2) + jj] = L[jj];
  }
  __syncthreads();
  float invL[4];
#pragma unroll
  for (int jj = 0; jj < 4; ++jj){
    int row = wr * 16 + ((lane >> 4) << 2) + jj;
    invL[jj] = 1.0f / (red[row] + red[32 + row] + red[64 + row] + red[96 + row] + 1e-20f);
  }

  // ---- Phase D: O += P x V^T (V transposed in-LDS: kvb[d][t])
  f32x4 o = {0.f, 0.f, 0.f, 0.f};
#pragma unroll
  for (int kt = 0; kt < 16; ++kt){
    int r = tid >> 3, sgc = tid & 7;
    us8 vv = *(const us8*)(qkv + ((size_t)(kt * 64 + r) * 8 + bat) * N3_ + head * 192 + 128 + sgc * 8);
    __syncthreads();
#pragma unroll
    for (int u = 0; u < 8; ++u){
      int d = sgc * 8 + u;
      *(u16*)((char*)kvb + d * 128 + ((r * 2) ^ ((d & 7) << 4))) = (u16)vv[u];
    }
    {
      int prow0 = wr * 16 + ((lane >> 4) << 2);
      int pcol = wc * 16 + (lane & 15);
#pragma unroll
      for (int jj = 0; jj < 4; ++jj){
        int prow = prow0 + jj;
        *(u16*)((char*)Pt + prow * 128 + ((pcol * 2) ^ ((prow & 7) << 4))) = f2b(p[kt][jj]);
      }
    }
    __syncthreads();
    int arow = wr * 16 + (lane & 15);
    int brow = wc * 16 + (lane & 15);
#pragma unroll
    for (int kk = 0; kk < 2; ++kk){
      int co = kk * 64 + ((lane >> 4) << 4);
      short8 a  = *(const short8*)((const char*)Pt + arow * 128 + (co ^ ((arow & 7) << 4)));
      short8 bv = *(const short8*)((const char*)kvb + brow * 128 + (co ^ ((brow & 7) << 4)));
      o = __builtin_amdgcn_mfma_f32_16x16x32_bf16(a, bv, o, 0, 0, 0);
    }
  }

  int d = wc * 16 + (lane & 15);
#pragma unroll
  for (int jj = 0; jj < 4; ++jj){
    int row = wr * 16 + ((lane >> 4) << 2) + jj;
    ctx[((size_t)(q0 + row) * 8 + bat) * 1024 + head * 64 + d] = f2b(o[jj] * invL[jj]);
  }
}

// ---------------- launch ----------------
extern "C" void kernel_launch(void* const* d_in, const int* in_sizes, int n_in,
                              void* d_out, int out_size, void* d_ws, size_t ws_size,
                              hipStream_t stream){
  const float* x   = (const float*)d_in[0];
  const float* pos = (const float*)d_in[1];
  const float* Wi  = (const float*)d_in[2];
  const float* bi  = (const float*)d_in[3];
  const float* Wp  = (const float*)d_in[4];
  const float* bp  = (const float*)d_in[5];
  const float* Wo  = (const float*)d_in[6];
  const float* bo  = (const float*)d_in[7];
  const float* r_i = (const float*)d_in[8];
  const float* s_i = (const float*)d_in[9];
  const float* r_p = (const float*)d_in[10];
  const float* s_p = (const float*)d_in[11];
  const float* rwb = (const float*)d_in[12];
  const float* rrb = (const float*)d_in[13];

  const size_t MB = 1024 * 1024;
  u16* qkv = (u16*)((char*)d_ws);              // 48 MiB (bf16)
  u16* rk  = (u16*)((char*)d_ws + 48 * MB);    // 16 MiB (bf16); total ws = 64 MiB
  float* out = (float*)d_out;

  // qkv = bf16((x*r_i) @ Wi^T * s_i + bi) ; rk = bf16((pos*r_p) @ Wp^T * s_p + bp)
  k_gemm<true,  true,  false, false, false><<<dim3(24, 64), 256, 0, stream>>>(x,   Wi, r_i, s_i, bi, qkv, N3_);
  k_gemm<true,  true,  true,  false, false><<<dim3(8, 64),  256, 0, stream>>>(pos, Wp, r_p, s_p, bp, rk, 1024);
  // attention: ctx (bf16) into d_out scratch, then stage into (now-dead) qkv region
  k_attn<<<dim3(128, 32), 512, 0, stream>>>(qkv, rk, rwb, rrb, (u16*)d_out);
  hipMemcpyAsync(qkv, d_out, (size_t)out_size * sizeof(u16), hipMemcpyDeviceToDevice, stream);
  // final projection: reads bf16 ctx, writes f32 d_out
  k_gemm<false, false, false, true, true><<<dim3(8, 64), 256, 0, stream>>>(qkv, Wo, nullptr, nullptr, bo, out, 1024);
}

// Round 5
// 511.225 us; speedup vs baseline: 1.4484x; 1.4484x over previous
//
#include <hip/hip_runtime.h>
#include <cstdint>
#include <cstddef>

using u16 = unsigned short;
typedef short short8 __attribute__((ext_vector_type(8)));
typedef unsigned short us8 __attribute__((ext_vector_type(8)));
typedef unsigned short us4 __attribute__((ext_vector_type(4)));
typedef float f32x4 __attribute__((ext_vector_type(4)));
typedef float f4 __attribute__((ext_vector_type(4)));

#define T_ 1024
#define B_ 8
#define H_ 1024
#define HEADS_ 16
#define HD_ 64
#define N3_ 3072

__device__ __forceinline__ float b2f(u16 u){
  union { float f; unsigned int i; } v; v.i = ((unsigned int)u) << 16; return v.f;
}
__device__ __forceinline__ u16 f2b(float f){
  union { float f; unsigned int i; } v; v.f = f;
  unsigned int r = v.i + 0x7fffu + ((v.i >> 16) & 1u);
  return (u16)(r >> 16);
}

// ---------------- GEMM (unchanged from passing round 4) ----------------
template<bool HAS_S, bool SCALE_A, bool POS_A, bool A_BF16, bool OUT_F32>
__global__ __launch_bounds__(256) void k_gemm(const void* __restrict__ A_, const float* __restrict__ W,
                                              const float* __restrict__ RA, const float* __restrict__ S,
                                              const float* __restrict__ bias, void* __restrict__ C_, int N){
  const int K = 1024;
  const int n0 = blockIdx.x * 128, m0 = blockIdx.y * 128;
  const int tid = threadIdx.x, lane = tid & 63;
  const int wave = tid >> 6, wr = wave >> 1, wc = wave & 1;
  __shared__ alignas(16) u16 At[128 * 32];
  __shared__ alignas(16) u16 Bt[128 * 32];
  f32x4 acc[4][4] = {};

  for (int kt = 0; kt < 32; ++kt){
    const int k0 = kt * 32;
    f4 wv[4];
    us8 avb[2];
    f4 avf[4];
#pragma unroll
    for (int i = 0; i < 4; ++i){
      int c = tid + i * 256, r = c >> 3, sg = c & 7;
      wv[i] = *(const f4*)(W + (size_t)(n0 + r) * K + k0 + sg * 4);
    }
    if (A_BF16){
      const u16* A = (const u16*)A_;
#pragma unroll
      for (int i = 0; i < 2; ++i){
        int c = tid + i * 256, r = c >> 2, sg = c & 3;
        avb[i] = *(const us8*)(A + (size_t)(m0 + r) * K + k0 + sg * 8);
      }
    } else {
      const float* A = (const float*)A_;
#pragma unroll
      for (int i = 0; i < 4; ++i){
        int c = tid + i * 256, r = c >> 3, sg = c & 7;
        int m = m0 + r;
        const float* ap = POS_A ? (A + (size_t)(m >> 3) * K + k0 + sg * 4)
                                : (A + (size_t)m * K + k0 + sg * 4);
        avf[i] = *(const f4*)ap;
        if (SCALE_A){
          f4 rv = *(const f4*)(RA + (m & 7) * K + k0 + sg * 4);
          avf[i] = avf[i] * rv;
        }
      }
    }
    __syncthreads();
#pragma unroll
    for (int i = 0; i < 4; ++i){
      int c = tid + i * 256, r = c >> 3, sg = c & 7;
      us4 pw;
#pragma unroll
      for (int u = 0; u < 4; ++u) pw[u] = f2b(wv[i][u]);
      *(us4*)(Bt + r * 32 + sg * 4) = pw;
    }
    if (A_BF16){
#pragma unroll
      for (int i = 0; i < 2; ++i){
        int c = tid + i * 256, r = c >> 2, sg = c & 3;
        *(us8*)(At + r * 32 + sg * 8) = avb[i];
      }
    } else {
#pragma unroll
      for (int i = 0; i < 4; ++i){
        int c = tid + i * 256, r = c >> 3, sg = c & 7;
        us4 pa;
#pragma unroll
        for (int u = 0; u < 4; ++u) pa[u] = f2b(avf[i][u]);
        *(us4*)(At + r * 32 + sg * 4) = pa;
      }
    }
    __syncthreads();
    short8 af[4], bf[4];
#pragma unroll
    for (int i = 0; i < 4; ++i){
      int ar = wr * 64 + i * 16 + (lane & 15);
      af[i] = *(const short8*)(At + ar * 32 + ((lane >> 4) << 3));
      int br = wc * 64 + i * 16 + (lane & 15);
      bf[i] = *(const short8*)(Bt + br * 32 + ((lane >> 4) << 3));
    }
#pragma unroll
    for (int i = 0; i < 4; ++i)
#pragma unroll
      for (int j = 0; j < 4; ++j)
        acc[i][j] = __builtin_amdgcn_mfma_f32_16x16x32_bf16(af[i], bf[j], acc[i][j], 0, 0, 0);
  }
#pragma unroll
  for (int i = 0; i < 4; ++i){
    int row0 = wr * 64 + i * 16 + ((lane >> 4) << 2);
#pragma unroll
    for (int j = 0; j < 4; ++j){
      int o = n0 + wc * 64 + j * 16 + (lane & 15);
      float bv = bias[o];
#pragma unroll
      for (int jj = 0; jj < 4; ++jj){
        int m = m0 + row0 + jj;
        float v = acc[i][j][jj];
        if (HAS_S) v *= S[(m & 7) * N + o];
        v += bv;
        if (OUT_F32) ((float*)C_)[(size_t)m * N + o] = v;
        else         ((u16*)C_)[(size_t)m * N + o] = f2b(v);
      }
    }
  }
}

// ---------------- V transpose to global: VT[n][d][t] <- qkv[t, b, head*192+128+d] ----------------
__global__ __launch_bounds__(256) void k_vt(const u16* __restrict__ qkv, u16* __restrict__ VT){
  const int tt = blockIdx.x;      // t-tile of 64
  const int n = blockIdx.y;       // 0..127
  const int b = n >> 4, head = n & 15;
  __shared__ alignas(16) u16 tile[64][72];
  const int tid = threadIdx.x;
#pragma unroll
  for (int i = 0; i < 2; ++i){
    int c = tid + i * 256;
    int r = c >> 3, sg = c & 7;
    const u16* src = qkv + ((size_t)(tt * 64 + r) * 8 + b) * N3_ + head * 192 + 128 + sg * 8;
    *(us8*)&tile[r][sg * 8] = *(const us8*)src;
  }
  __syncthreads();
#pragma unroll
  for (int i = 0; i < 2; ++i){
    int c = tid + i * 256;
    int d = c >> 3, sg = c & 7;
    us8 ov;
#pragma unroll
    for (int u = 0; u < 8; ++u) ov[u] = tile[sg * 8 + u][d];
    *(us8*)(VT + ((size_t)n * 64 + d) * 1024 + tt * 64 + sg * 8) = ov;
  }
}

// ---------------- fused attention, restructured ----------------
// grid (128 n, 32 qb), 512 thr (8 waves). Per block: 32 q rows x 1024 k. 512-col segments.
#define G_OFF   0           // g[33][1028] u16 = 67848 B ; Phase D: Pt_w overlay (8 x 8192)
#define KV_OFF  67856       // staging 65536 B (K/rk rows x 64d, 128B rows) ; D: VT[64][512] 1024B rows ; then f32 partials
#define RWQ_OFF 133392      // 32 x 128B
#define RRQ_OFF 137488      // 48 x 128B
#define RED_OFF 143632      // 544 floats
#define SMEM_SZ 145808

__global__ __launch_bounds__(512, 1) void k_attn(const u16* __restrict__ qkv, const u16* __restrict__ rk,
                                                 const u16* __restrict__ VTg, const float* __restrict__ rwb,
                                                 const float* __restrict__ rrb, u16* __restrict__ ctx){
  const int n = blockIdx.x, qb = blockIdx.y, q0 = qb * 32;
  const int bat = n >> 4, head = n & 15;
  const int tid = threadIdx.x, lane = tid & 63, wave = tid >> 6;
  const int l15 = lane & 15, grp = lane >> 4;

  __shared__ alignas(16) char smem[SMEM_SZ];
  u16* gS  = (u16*)(smem + G_OFF);
  char* kvS = smem + KV_OFF;
  u16* rwq = (u16*)(smem + RWQ_OFF);
  u16* rrq = (u16*)(smem + RRQ_OFF);
  float* redf = (float*)(smem + RED_OFF);

  // ---- Phase A: rw_q (32 rows) + rr_q (48 rows), bias added, bf16, 128B swizzled rows
#pragma unroll
  for (int rep = 0; rep < 2; ++rep){
    int c = tid + rep * 512;
    if (c < 640){
      int s = c >> 3, sg = c & 7;
      u16* dst; int row; const float* bias;
      if (s < 32){ dst = rwq; row = s; bias = rwb; }
      else       { dst = rrq; row = s - 32; bias = rrb; }
      int qrow = q0 + row;
      float v[8];
      const float* bp2 = bias + head * 64 + sg * 8;
      if (qrow < T_){
        const u16* qp = qkv + ((size_t)qrow * 8 + bat) * N3_ + head * 192 + sg * 8;
        us8 qv = *(const us8*)qp;
        f4 b0 = *(const f4*)bp2, b1 = *(const f4*)(bp2 + 4);
#pragma unroll
        for (int u = 0; u < 4; ++u){ v[u] = b2f(qv[u]) + b0[u]; v[u + 4] = b2f(qv[u + 4]) + b1[u]; }
      } else {
#pragma unroll
        for (int u = 0; u < 8; ++u) v[u] = 0.f;
      }
      us8 pk;
#pragma unroll
      for (int u = 0; u < 8; ++u) pk[u] = f2b(v[u]);
      *(us8*)((char*)dst + row * 128 + ((sg * 16) ^ ((row & 7) << 4))) = pk;
    }
  }

  // fragment loader from 128B-row swizzled tiles
  auto ldf = [&](const void* base, int row, int kkb)->short8 {
    int co = kkb + (grp << 4);
    return *(const short8*)((const char*)base + row * 128 + (co ^ ((row & 7) << 4)));
  };

  us8 stv[8];

  // ---- Phase B: g[a][r] = rr_q[q0+a].rk[r], a<33, r in [0,1024). 2 segments of 512 r.
#pragma unroll
  for (int i = 0; i < 8; ++i){ int c = tid + i * 512, r = c >> 3, sg = c & 7;
    stv[i] = *(const us8*)(rk + ((size_t)r * 8 + bat) * 1024 + head * 64 + sg * 8); }
  __syncthreads();                 // Phase A visible
#pragma unroll
  for (int i = 0; i < 8; ++i){ int c = tid + i * 512, r = c >> 3, sg = c & 7;
    *(us8*)(kvS + r * 128 + ((sg * 16) ^ ((r & 7) << 4))) = stv[i]; }
#pragma unroll
  for (int i = 0; i < 8; ++i){ int c = tid + i * 512, r = c >> 3, sg = c & 7;
    stv[i] = *(const us8*)(rk + ((size_t)(512 + r) * 8 + bat) * 1024 + head * 64 + sg * 8); }
  __syncthreads();                 // seg0 staged

#pragma unroll
  for (int s = 0; s < 2; ++s){
    short8 af[3][2];
#pragma unroll
    for (int pi = 0; pi < 3; ++pi)
#pragma unroll
      for (int kk = 0; kk < 2; ++kk) af[pi][kk] = ldf(rrq, pi * 16 + l15, kk * 64);
#pragma unroll
    for (int c4 = 0; c4 < 4; ++c4){
      int brow = wave * 64 + c4 * 16 + l15;
      short8 bf0 = ldf(kvS, brow, 0), bf1 = ldf(kvS, brow, 64);
      int rg = s * 512 + wave * 64 + c4 * 16 + l15;
#pragma unroll
      for (int pi = 0; pi < 3; ++pi){
        f32x4 acc = {0.f, 0.f, 0.f, 0.f};
        acc = __builtin_amdgcn_mfma_f32_16x16x32_bf16(af[pi][0], bf0, acc, 0, 0, 0);
        acc = __builtin_amdgcn_mfma_f32_16x16x32_bf16(af[pi][1], bf1, acc, 0, 0, 0);
#pragma unroll
        for (int jj = 0; jj < 4; ++jj){
          int a = pi * 16 + (grp << 2) + jj;
          if (a < 33) gS[a * 1028 + rg] = f2b(acc[jj]);
        }
      }
    }
    if (s == 0){
      __syncthreads();             // seg0 readers done
#pragma unroll
      for (int i = 0; i < 8; ++i){ int c = tid + i * 512, r = c >> 3, sg = c & 7;
        *(us8*)(kvS + r * 128 + ((sg * 16) ^ ((r & 7) << 4))) = stv[i]; }
      __syncthreads();
    }
  }

  // ---- Phase C: scores = AC + rel-shifted BD (gather from gS), kept in registers
  f32x4 p[2][2][4];
  float pm[2][4];
#pragma unroll
  for (int m = 0; m < 2; ++m)
#pragma unroll
    for (int jj = 0; jj < 4; ++jj) pm[m][jj] = -3.0e38f;

#pragma unroll
  for (int i = 0; i < 8; ++i){ int c = tid + i * 512, r = c >> 3, sg = c & 7;
    stv[i] = *(const us8*)(qkv + ((size_t)r * 8 + bat) * N3_ + head * 192 + 64 + sg * 8); }
  __syncthreads();                 // Phase B seg1 readers done
#pragma unroll
  for (int i = 0; i < 8; ++i){ int c = tid + i * 512, r = c >> 3, sg = c & 7;
    *(us8*)(kvS + r * 128 + ((sg * 16) ^ ((r & 7) << 4))) = stv[i]; }
#pragma unroll
  for (int i = 0; i < 8; ++i){ int c = tid + i * 512, r = c >> 3, sg = c & 7;
    stv[i] = *(const us8*)(qkv + ((size_t)(512 + r) * 8 + bat) * N3_ + head * 192 + 64 + sg * 8); }
  __syncthreads();

#pragma unroll
  for (int s = 0; s < 2; ++s){
    short8 af[2][2];
#pragma unroll
    for (int m = 0; m < 2; ++m)
#pragma unroll
      for (int kk = 0; kk < 2; ++kk) af[m][kk] = ldf(rwq, m * 16 + l15, kk * 64);
#pragma unroll
    for (int c4 = 0; c4 < 4; ++c4){
      int brow = wave * 64 + c4 * 16 + l15;
      short8 bf0 = ldf(kvS, brow, 0), bf1 = ldf(kvS, brow, 64);
      int bcol = s * 512 + wave * 64 + c4 * 16 + l15;
#pragma unroll
      for (int m = 0; m < 2; ++m){
        f32x4 acc = {0.f, 0.f, 0.f, 0.f};
        acc = __builtin_amdgcn_mfma_f32_16x16x32_bf16(af[m][0], bf0, acc, 0, 0, 0);
        acc = __builtin_amdgcn_mfma_f32_16x16x32_bf16(af[m][1], bf1, acc, 0, 0, 0);
#pragma unroll
        for (int jj = 0; jj < 4; ++jj){
          int aa = m * 16 + (grp << 2) + jj;
          int a_ = q0 + aa;
          float gv;
          if (bcol <= a_)          gv = b2f(gS[aa * 1028 + 1023 - a_ + bcol]);
          else if (bcol == a_ + 1) gv = 0.0f;
          else                     gv = b2f(gS[(aa + 1) * 1028 + bcol - a_ - 2]);
          float sc = (acc[jj] + gv) * 0.125f;
          p[s][m][c4][jj] = sc;
          pm[m][jj] = fmaxf(pm[m][jj], sc);
        }
      }
    }
    if (s == 0){
      __syncthreads();
#pragma unroll
      for (int i = 0; i < 8; ++i){ int c = tid + i * 512, r = c >> 3, sg = c & 7;
        *(us8*)(kvS + r * 128 + ((sg * 16) ^ ((r & 7) << 4))) = stv[i]; }
      __syncthreads();
    }
  }

  // ---- softmax (exact two-pass)
#pragma unroll
  for (int m = 0; m < 2; ++m)
#pragma unroll
    for (int jj = 0; jj < 4; ++jj)
#pragma unroll
      for (int mk = 1; mk < 16; mk <<= 1) pm[m][jj] = fmaxf(pm[m][jj], __shfl_xor(pm[m][jj], mk));
  __syncthreads();                 // Phase C kvS/gS readers done
  if (l15 == 0){
#pragma unroll
    for (int m = 0; m < 2; ++m)
#pragma unroll
      for (int jj = 0; jj < 4; ++jj) redf[wave * 32 + m * 16 + (grp << 2) + jj] = pm[m][jj];
  }
  __syncthreads();
  float M_[2][4];
#pragma unroll
  for (int m = 0; m < 2; ++m)
#pragma unroll
    for (int jj = 0; jj < 4; ++jj){
      int row = m * 16 + (grp << 2) + jj;
      float v = redf[row];
#pragma unroll
      for (int w = 1; w < 8; ++w) v = fmaxf(v, redf[w * 32 + row]);
      M_[m][jj] = v;
    }
  float L_[2][4] = {};
#pragma unroll
  for (int s = 0; s < 2; ++s)
#pragma unroll
    for (int m = 0; m < 2; ++m)
#pragma unroll
      for (int c4 = 0; c4 < 4; ++c4)
#pragma unroll
        for (int jj = 0; jj < 4; ++jj){
          float e = __expf(fminf(p[s][m][c4][jj] - M_[m][jj], 0.f));
          p[s][m][c4][jj] = e;
          L_[m][jj] += e;
        }
#pragma unroll
  for (int m = 0; m < 2; ++m)
#pragma unroll
    for (int jj = 0; jj < 4; ++jj)
#pragma unroll
      for (int mk = 1; mk < 16; mk <<= 1) L_[m][jj] += __shfl_xor(L_[m][jj], mk);
  if (l15 == 0){
#pragma unroll
    for (int m = 0; m < 2; ++m)
#pragma unroll
      for (int jj = 0; jj < 4; ++jj) redf[256 + wave * 32 + m * 16 + (grp << 2) + jj] = L_[m][jj];
  }
  __syncthreads();
  if (wave == 0 && l15 == 0){
#pragma unroll
    for (int m = 0; m < 2; ++m)
#pragma unroll
      for (int jj = 0; jj < 4; ++jj){
        int row = m * 16 + (grp << 2) + jj;
        float sum = 0.f;
#pragma unroll
        for (int w = 0; w < 8; ++w) sum += redf[256 + w * 32 + row];
        redf[512 + row] = 1.0f / (sum + 1e-20f);
      }
  }

  // ---- Phase D: O = P x V. Wave w reduces its own t-columns; Pt is per-wave private (gS overlay).
  char* ptW = smem + G_OFF + wave * 8192;   // [32 q][128 tl] u16, 256B rows, swizzled
#pragma unroll
  for (int s = 0; s < 2; ++s)
#pragma unroll
    for (int m = 0; m < 2; ++m)
#pragma unroll
      for (int c4 = 0; c4 < 4; ++c4)
#pragma unroll
        for (int jj = 0; jj < 4; ++jj){
          int q = m * 16 + (grp << 2) + jj;
          int tl = s * 64 + c4 * 16 + l15;
          *(u16*)(ptW + q * 256 + ((tl * 2) ^ ((q & 7) << 4))) = f2b(p[s][m][c4][jj]);
        }
  // stage VT seg0: rows d (64) x 512 t, 1024B rows, XOR (d&31)<<4
#pragma unroll
  for (int i = 0; i < 8; ++i){ int c = tid + i * 512, d = c >> 6, tc = c & 63;
    stv[i] = *(const us8*)(VTg + ((size_t)n * 64 + d) * 1024 + tc * 8); }
  __syncthreads();                 // all waves past softmax (kvS free), redf[512+] visible later
#pragma unroll
  for (int i = 0; i < 8; ++i){ int c = tid + i * 512, d = c >> 6, tc = c & 63;
    *(us8*)(kvS + d * 1024 + ((tc * 16) ^ ((d & 31) << 4))) = stv[i]; }
#pragma unroll
  for (int i = 0; i < 8; ++i){ int c = tid + i * 512, d = c >> 6, tc = c & 63;
    stv[i] = *(const us8*)(VTg + ((size_t)n * 64 + d) * 1024 + 512 + tc * 8); }
  __syncthreads();

  f32x4 Oacc[2][4] = {};
#pragma unroll
  for (int s = 0; s < 2; ++s){
#pragma unroll
    for (int kk = 0; kk < 2; ++kk){
      short8 pa[2];
#pragma unroll
      for (int m = 0; m < 2; ++m)
        pa[m] = *(const short8*)(ptW + (m * 16 + l15) * 256 + ((s * 128 + kk * 64 + (grp << 4)) ^ ((l15 & 7) << 4)));
#pragma unroll
      for (int dt = 0; dt < 4; ++dt){
        int dr = dt * 16 + l15;
        short8 vb = *(const short8*)(kvS + dr * 1024 + ((wave * 128 + kk * 64 + (grp << 4)) ^ ((dr & 31) << 4)));
#pragma unroll
        for (int m = 0; m < 2; ++m)
          Oacc[m][dt] = __builtin_amdgcn_mfma_f32_16x16x32_bf16(pa[m], vb, Oacc[m][dt], 0, 0, 0);
      }
    }
    if (s == 0){
      __syncthreads();
#pragma unroll
      for (int i = 0; i < 8; ++i){ int c = tid + i * 512, d = c >> 6, tc = c & 63;
        *(us8*)(kvS + d * 1024 + ((tc * 16) ^ ((d & 31) << 4))) = stv[i]; }
      __syncthreads();
    }
  }

  // cross-wave reduce of partial O (8 x [32 q][64 d] f32 in kvS region)
  __syncthreads();
  float* par = (float*)kvS;
#pragma unroll
  for (int m = 0; m < 2; ++m)
#pragma unroll
    for (int dt = 0; dt < 4; ++dt)
#pragma unroll
      for (int jj = 0; jj < 4; ++jj)
        par[wave * 2048 + (m * 16 + (grp << 2) + jj) * 64 + dt * 16 + l15] = Oacc[m][dt][jj];
  __syncthreads();
  {
    f32x4 v = {0.f, 0.f, 0.f, 0.f};
#pragma unroll
    for (int w = 0; w < 8; ++w) v += *(const f32x4*)(par + w * 2048 + tid * 4);
    int q = tid >> 4, d4 = (tid & 15) * 4;
    float il = redf[512 + q];
    us4 pk;
#pragma unroll
    for (int e = 0; e < 4; ++e) pk[e] = f2b(v[e] * il);
    *(us4*)(ctx + ((size_t)(q0 + q) * 8 + bat) * 1024 + head * 64 + d4) = pk;
  }
}

// ---------------- launch ----------------
extern "C" void kernel_launch(void* const* d_in, const int* in_sizes, int n_in,
                              void* d_out, int out_size, void* d_ws, size_t ws_size,
                              hipStream_t stream){
  const float* x   = (const float*)d_in[0];
  const float* pos = (const float*)d_in[1];
  const float* Wi  = (const float*)d_in[2];
  const float* bi  = (const float*)d_in[3];
  const float* Wp  = (const float*)d_in[4];
  const float* bp  = (const float*)d_in[5];
  const float* Wo  = (const float*)d_in[6];
  const float* bo  = (const float*)d_in[7];
  const float* r_i = (const float*)d_in[8];
  const float* s_i = (const float*)d_in[9];
  const float* r_p = (const float*)d_in[10];
  const float* s_p = (const float*)d_in[11];
  const float* rwb = (const float*)d_in[12];
  const float* rrb = (const float*)d_in[13];

  const size_t MB = 1024 * 1024;
  u16* qkv = (u16*)((char*)d_ws);              // 48 MiB (bf16)
  u16* rk  = (u16*)((char*)d_ws + 48 * MB);    // 16 MiB (bf16); ws total 64 MiB
  // d_out (33.55 MB) used as scratch: VT bf16 16.78 MB at [0], ctx bf16 16.78 MB at [16.78MB]
  u16* VTg  = (u16*)d_out;
  u16* ctxg = (u16*)((char*)d_out + 16777216);

  k_gemm<true,  true,  false, false, false><<<dim3(24, 64), 256, 0, stream>>>(x,   Wi, r_i, s_i, bi, qkv, N3_);
  k_gemm<true,  true,  true,  false, false><<<dim3(8, 64),  256, 0, stream>>>(pos, Wp, r_p, s_p, bp, rk, 1024);
  k_vt<<<dim3(16, 128), 256, 0, stream>>>(qkv, VTg);
  k_attn<<<dim3(128, 32), 512, 0, stream>>>(qkv, rk, VTg, rwb, rrb, ctxg);
  hipMemcpyAsync(qkv, ctxg, (size_t)out_size * sizeof(u16), hipMemcpyDeviceToDevice, stream);
  k_gemm<false, false, false, true, true><<<dim3(8, 64), 256, 0, stream>>>(qkv, Wo, nullptr, nullptr, bo, (float*)d_out, 1024);
}

// Round 6
// 451.646 us; speedup vs baseline: 1.6395x; 1.1319x over previous
//
#include <hip/hip_runtime.h>
#include <cstdint>
#include <cstddef>

using u16 = unsigned short;
typedef short short8 __attribute__((ext_vector_type(8)));
typedef unsigned short us8 __attribute__((ext_vector_type(8)));
typedef unsigned short us4 __attribute__((ext_vector_type(4)));
typedef float f32x4 __attribute__((ext_vector_type(4)));
typedef float f4 __attribute__((ext_vector_type(4)));

#define T_ 1024
#define B_ 8
#define H_ 1024
#define HEADS_ 16
#define HD_ 64
#define N3_ 3072

__device__ __forceinline__ float b2f(u16 u){
  union { float f; unsigned int i; } v; v.i = ((unsigned int)u) << 16; return v.f;
}
// fast bf16 convert: round-half-up (2 VALU ops vs 4 for RTNE; <=0.5 ulp, ties differ only)
__device__ __forceinline__ u16 f2b(float f){
  union { float f; unsigned int i; } v; v.f = f;
  return (u16)((v.i + 0x8000u) >> 16);
}

// ---------------- GEMM (structure unchanged from passing rounds; f2b now fast) ----------------
template<bool HAS_S, bool SCALE_A, bool POS_A, bool A_BF16, bool OUT_F32>
__global__ __launch_bounds__(256) void k_gemm(const void* __restrict__ A_, const float* __restrict__ W,
                                              const float* __restrict__ RA, const float* __restrict__ S,
                                              const float* __restrict__ bias, void* __restrict__ C_, int N){
  const int K = 1024;
  const int n0 = blockIdx.x * 128, m0 = blockIdx.y * 128;
  const int tid = threadIdx.x, lane = tid & 63;
  const int wave = tid >> 6, wr = wave >> 1, wc = wave & 1;
  __shared__ alignas(16) u16 At[128 * 32];
  __shared__ alignas(16) u16 Bt[128 * 32];
  f32x4 acc[4][4] = {};

  for (int kt = 0; kt < 32; ++kt){
    const int k0 = kt * 32;
    f4 wv[4];
    us8 avb[2];
    f4 avf[4];
#pragma unroll
    for (int i = 0; i < 4; ++i){
      int c = tid + i * 256, r = c >> 3, sg = c & 7;
      wv[i] = *(const f4*)(W + (size_t)(n0 + r) * K + k0 + sg * 4);
    }
    if (A_BF16){
      const u16* A = (const u16*)A_;
#pragma unroll
      for (int i = 0; i < 2; ++i){
        int c = tid + i * 256, r = c >> 2, sg = c & 3;
        avb[i] = *(const us8*)(A + (size_t)(m0 + r) * K + k0 + sg * 8);
      }
    } else {
      const float* A = (const float*)A_;
#pragma unroll
      for (int i = 0; i < 4; ++i){
        int c = tid + i * 256, r = c >> 3, sg = c & 7;
        int m = m0 + r;
        const float* ap = POS_A ? (A + (size_t)(m >> 3) * K + k0 + sg * 4)
                                : (A + (size_t)m * K + k0 + sg * 4);
        avf[i] = *(const f4*)ap;
        if (SCALE_A){
          f4 rv = *(const f4*)(RA + (m & 7) * K + k0 + sg * 4);
          avf[i] = avf[i] * rv;
        }
      }
    }
    __syncthreads();
#pragma unroll
    for (int i = 0; i < 4; ++i){
      int c = tid + i * 256, r = c >> 3, sg = c & 7;
      us4 pw;
#pragma unroll
      for (int u = 0; u < 4; ++u) pw[u] = f2b(wv[i][u]);
      *(us4*)(Bt + r * 32 + sg * 4) = pw;
    }
    if (A_BF16){
#pragma unroll
      for (int i = 0; i < 2; ++i){
        int c = tid + i * 256, r = c >> 2, sg = c & 3;
        *(us8*)(At + r * 32 + sg * 8) = avb[i];
      }
    } else {
#pragma unroll
      for (int i = 0; i < 4; ++i){
        int c = tid + i * 256, r = c >> 3, sg = c & 7;
        us4 pa;
#pragma unroll
        for (int u = 0; u < 4; ++u) pa[u] = f2b(avf[i][u]);
        *(us4*)(At + r * 32 + sg * 4) = pa;
      }
    }
    __syncthreads();
    short8 af[4], bf[4];
#pragma unroll
    for (int i = 0; i < 4; ++i){
      int ar = wr * 64 + i * 16 + (lane & 15);
      af[i] = *(const short8*)(At + ar * 32 + ((lane >> 4) << 3));
      int br = wc * 64 + i * 16 + (lane & 15);
      bf[i] = *(const short8*)(Bt + br * 32 + ((lane >> 4) << 3));
    }
#pragma unroll
    for (int i = 0; i < 4; ++i)
#pragma unroll
      for (int j = 0; j < 4; ++j)
        acc[i][j] = __builtin_amdgcn_mfma_f32_16x16x32_bf16(af[i], bf[j], acc[i][j], 0, 0, 0);
  }
#pragma unroll
  for (int i = 0; i < 4; ++i){
    int row0 = wr * 64 + i * 16 + ((lane >> 4) << 2);
#pragma unroll
    for (int j = 0; j < 4; ++j){
      int o = n0 + wc * 64 + j * 16 + (lane & 15);
      float bv = bias[o];
#pragma unroll
      for (int jj = 0; jj < 4; ++jj){
        int m = m0 + row0 + jj;
        float v = acc[i][j][jj];
        if (HAS_S) v *= S[(m & 7) * N + o];
        v += bv;
        if (OUT_F32) ((float*)C_)[(size_t)m * N + o] = v;
        else         ((u16*)C_)[(size_t)m * N + o] = f2b(v);
      }
    }
  }
}

// ---------------- V transpose to global: VT[n][d][t] <- qkv[t, b, head*192+128+d] ----------------
__global__ __launch_bounds__(256) void k_vt(const u16* __restrict__ qkv, u16* __restrict__ VT){
  const int tt = blockIdx.x;      // t-tile of 64
  const int n = blockIdx.y;       // 0..127
  const int b = n >> 4, head = n & 15;
  __shared__ alignas(16) u16 tile[64][72];
  const int tid = threadIdx.x;
#pragma unroll
  for (int i = 0; i < 2; ++i){
    int c = tid + i * 256;
    int r = c >> 3, sg = c & 7;
    const u16* src = qkv + ((size_t)(tt * 64 + r) * 8 + b) * N3_ + head * 192 + 128 + sg * 8;
    *(us8*)&tile[r][sg * 8] = *(const us8*)src;
  }
  __syncthreads();
#pragma unroll
  for (int i = 0; i < 2; ++i){
    int c = tid + i * 256;
    int d = c >> 3, sg = c & 7;
    us8 ov;
#pragma unroll
    for (int u = 0; u < 8; ++u) ov[u] = tile[sg * 8 + u][d];
    *(us8*)(VT + ((size_t)n * 64 + d) * 1024 + tt * 64 + sg * 8) = ov;
  }
}

// ---------------- fused attention ----------------
// grid (128 n, 32 qb), 512 thr (8 waves). 32 q rows x 1024 k per block, 512-col segments.
// gS: FLAT rel-shift layout, g[a][r] at element a*1025+r, slot a*1025+1024 zeroed ->
//     gv = gS[aa*1024 + (1023-q0+bcol)] covers all three rel_shift branches, branchless.
// gS bytes XOR-swizzled: byte ^= ((byte>>13)&3)<<5 (conflict-free gathers).
#define G_OFF   0           // 33*1025*2 = 67650 B ; Phase D: Pt_w overlay (8 x 8192)
#define KV_OFF  67856       // staging 65536 B ; Phase D: VT[64][512] then f32 partials
#define RWQ_OFF 133392      // 32 x 128B
#define RRQ_OFF 137488      // 48 x 128B
#define RED_OFF 143632      // 544 floats
#define SMEM_SZ 145808

__device__ __forceinline__ int gswz(int byt){ return byt ^ (((byt >> 13) & 3) << 5); }

__global__ __launch_bounds__(512, 1) void k_attn(const u16* __restrict__ qkv, const u16* __restrict__ rk,
                                                 const u16* __restrict__ VTg, const float* __restrict__ rwb,
                                                 const float* __restrict__ rrb, u16* __restrict__ ctx){
  const int n = blockIdx.x, qb = blockIdx.y, q0 = qb * 32;
  const int bat = n >> 4, head = n & 15;
  const int tid = threadIdx.x, lane = tid & 63, wave = tid >> 6;
  const int l15 = lane & 15, grp = lane >> 4;

  __shared__ alignas(16) char smem[SMEM_SZ];
  char* gB  = smem + G_OFF;
  char* kvS = smem + KV_OFF;
  u16* rwq = (u16*)(smem + RWQ_OFF);
  u16* rrq = (u16*)(smem + RRQ_OFF);
  float* redf = (float*)(smem + RED_OFF);

  // ---- Phase A: rw_q (32 rows) + rr_q (48 rows), bias added, pre-scaled by 0.125 (exact pow2)
#pragma unroll
  for (int rep = 0; rep < 2; ++rep){
    int c = tid + rep * 512;
    if (c < 640){
      int s = c >> 3, sg = c & 7;
      u16* dst; int row; const float* bias;
      if (s < 32){ dst = rwq; row = s; bias = rwb; }
      else       { dst = rrq; row = s - 32; bias = rrb; }
      int qrow = q0 + row;
      float v[8];
      const float* bp2 = bias + head * 64 + sg * 8;
      if (qrow < T_){
        const u16* qp = qkv + ((size_t)qrow * 8 + bat) * N3_ + head * 192 + sg * 8;
        us8 qv = *(const us8*)qp;
        f4 b0 = *(const f4*)bp2, b1 = *(const f4*)(bp2 + 4);
#pragma unroll
        for (int u = 0; u < 4; ++u){
          v[u]     = (b2f(qv[u])     + b0[u]) * 0.125f;
          v[u + 4] = (b2f(qv[u + 4]) + b1[u]) * 0.125f;
        }
      } else {
#pragma unroll
        for (int u = 0; u < 8; ++u) v[u] = 0.f;
      }
      us8 pk;
#pragma unroll
      for (int u = 0; u < 8; ++u) pk[u] = f2b(v[u]);
      *(us8*)((char*)dst + row * 128 + ((sg * 16) ^ ((row & 7) << 4))) = pk;
    }
  }
  // zero the 33 rel-shift slots (element a*1025+1024)
  if (tid < 33) *(u16*)(gB + gswz(tid * 2050 + 2048)) = 0;

  // fragment loader from 128B-row swizzled tiles
  auto ldf = [&](const void* base, int row, int kkb)->short8 {
    int co = kkb + (grp << 4);
    return *(const short8*)((const char*)base + row * 128 + (co ^ ((row & 7) << 4)));
  };

  us8 stv[8];

  // ---- Phase B: g[a][r] = rr_q[q0+a].rk[r], a<33 (pre-scaled). Flat-1025 store.
#pragma unroll
  for (int i = 0; i < 8; ++i){ int c = tid + i * 512, r = c >> 3, sg = c & 7;
    stv[i] = *(const us8*)(rk + ((size_t)r * 8 + bat) * 1024 + head * 64 + sg * 8); }
  __syncthreads();                 // Phase A + zero slots visible
#pragma unroll
  for (int i = 0; i < 8; ++i){ int c = tid + i * 512, r = c >> 3, sg = c & 7;
    *(us8*)(kvS + r * 128 + ((sg * 16) ^ ((r & 7) << 4))) = stv[i]; }
#pragma unroll
  for (int i = 0; i < 8; ++i){ int c = tid + i * 512, r = c >> 3, sg = c & 7;
    stv[i] = *(const us8*)(rk + ((size_t)(512 + r) * 8 + bat) * 1024 + head * 64 + sg * 8); }
  __syncthreads();                 // seg0 staged

#pragma unroll
  for (int s = 0; s < 2; ++s){
    short8 af[3][2];
#pragma unroll
    for (int pi = 0; pi < 3; ++pi)
#pragma unroll
      for (int kk = 0; kk < 2; ++kk) af[pi][kk] = ldf(rrq, pi * 16 + l15, kk * 64);
#pragma unroll
    for (int c4 = 0; c4 < 4; ++c4){
      int brow = wave * 64 + c4 * 16 + l15;
      short8 bf0 = ldf(kvS, brow, 0), bf1 = ldf(kvS, brow, 64);
      int rg = s * 512 + wave * 64 + c4 * 16 + l15;
#pragma unroll
      for (int pi = 0; pi < 3; ++pi){
        f32x4 acc = {0.f, 0.f, 0.f, 0.f};
        acc = __builtin_amdgcn_mfma_f32_16x16x32_bf16(af[pi][0], bf0, acc, 0, 0, 0);
        acc = __builtin_amdgcn_mfma_f32_16x16x32_bf16(af[pi][1], bf1, acc, 0, 0, 0);
#pragma unroll
        for (int jj = 0; jj < 4; ++jj){
          int a = pi * 16 + (grp << 2) + jj;
          if (a < 33) *(u16*)(gB + gswz(a * 2050 + (rg << 1))) = f2b(acc[jj]);
        }
      }
    }
    if (s == 0){
      __syncthreads();             // seg0 readers done
#pragma unroll
      for (int i = 0; i < 8; ++i){ int c = tid + i * 512, r = c >> 3, sg = c & 7;
        *(us8*)(kvS + r * 128 + ((sg * 16) ^ ((r & 7) << 4))) = stv[i]; }
      __syncthreads();
    }
  }

  // ---- Phase C: scores = AC + rel-shifted BD (branchless flat gather), kept in registers
  f32x4 p[2][2][4];
  float pm[2][4];
#pragma unroll
  for (int m = 0; m < 2; ++m)
#pragma unroll
    for (int jj = 0; jj < 4; ++jj) pm[m][jj] = -3.0e38f;

#pragma unroll
  for (int i = 0; i < 8; ++i){ int c = tid + i * 512, r = c >> 3, sg = c & 7;
    stv[i] = *(const us8*)(qkv + ((size_t)r * 8 + bat) * N3_ + head * 192 + 64 + sg * 8); }
  __syncthreads();                 // Phase B readers (and gS writers) done
#pragma unroll
  for (int i = 0; i < 8; ++i){ int c = tid + i * 512, r = c >> 3, sg = c & 7;
    *(us8*)(kvS + r * 128 + ((sg * 16) ^ ((r & 7) << 4))) = stv[i]; }
#pragma unroll
  for (int i = 0; i < 8; ++i){ int c = tid + i * 512, r = c >> 3, sg = c & 7;
    stv[i] = *(const us8*)(qkv + ((size_t)(512 + r) * 8 + bat) * N3_ + head * 192 + 64 + sg * 8); }
  __syncthreads();

#pragma unroll
  for (int s = 0; s < 2; ++s){
    short8 af[2][2];
#pragma unroll
    for (int m = 0; m < 2; ++m)
#pragma unroll
      for (int kk = 0; kk < 2; ++kk) af[m][kk] = ldf(rwq, m * 16 + l15, kk * 64);
#pragma unroll
    for (int c4 = 0; c4 < 4; ++c4){
      int brow = wave * 64 + c4 * 16 + l15;
      short8 bf0 = ldf(kvS, brow, 0), bf1 = ldf(kvS, brow, 64);
      int bcol = s * 512 + wave * 64 + c4 * 16 + l15;
      int byt0 = ((1023 - q0 + bcol) << 1) + (grp << 13);
#pragma unroll
      for (int m = 0; m < 2; ++m){
        f32x4 acc = {0.f, 0.f, 0.f, 0.f};
        acc = __builtin_amdgcn_mfma_f32_16x16x32_bf16(af[m][0], bf0, acc, 0, 0, 0);
        acc = __builtin_amdgcn_mfma_f32_16x16x32_bf16(af[m][1], bf1, acc, 0, 0, 0);
#pragma unroll
        for (int jj = 0; jj < 4; ++jj){
          int byt = byt0 + (m << 15) + (jj << 11);
          float gv = b2f(*(const u16*)(gB + gswz(byt)));
          float sc = acc[jj] + gv;
          p[s][m][c4][jj] = sc;
          pm[m][jj] = fmaxf(pm[m][jj], sc);
        }
      }
    }
    if (s == 0){
      __syncthreads();
#pragma unroll
      for (int i = 0; i < 8; ++i){ int c = tid + i * 512, r = c >> 3, sg = c & 7;
        *(us8*)(kvS + r * 128 + ((sg * 16) ^ ((r & 7) << 4))) = stv[i]; }
      __syncthreads();
    }
  }

  // ---- softmax (exact two-pass)
#pragma unroll
  for (int m = 0; m < 2; ++m)
#pragma unroll
    for (int jj = 0; jj < 4; ++jj)
#pragma unroll
      for (int mk = 1; mk < 16; mk <<= 1) pm[m][jj] = fmaxf(pm[m][jj], __shfl_xor(pm[m][jj], mk));
  __syncthreads();                 // Phase C kvS/gS readers done
  if (l15 == 0){
#pragma unroll
    for (int m = 0; m < 2; ++m)
#pragma unroll
      for (int jj = 0; jj < 4; ++jj) redf[wave * 32 + m * 16 + (grp << 2) + jj] = pm[m][jj];
  }
  __syncthreads();
  float M_[2][4];
#pragma unroll
  for (int m = 0; m < 2; ++m)
#pragma unroll
    for (int jj = 0; jj < 4; ++jj){
      int row = m * 16 + (grp << 2) + jj;
      float v = redf[row];
#pragma unroll
      for (int w = 1; w < 8; ++w) v = fmaxf(v, redf[w * 32 + row]);
      M_[m][jj] = v;
    }
  float L_[2][4] = {};
#pragma unroll
  for (int s = 0; s < 2; ++s)
#pragma unroll
    for (int m = 0; m < 2; ++m)
#pragma unroll
      for (int c4 = 0; c4 < 4; ++c4)
#pragma unroll
        for (int jj = 0; jj < 4; ++jj){
          float e = __expf(fminf(p[s][m][c4][jj] - M_[m][jj], 0.f));
          p[s][m][c4][jj] = e;
          L_[m][jj] += e;
        }
#pragma unroll
  for (int m = 0; m < 2; ++m)
#pragma unroll
    for (int jj = 0; jj < 4; ++jj)
#pragma unroll
      for (int mk = 1; mk < 16; mk <<= 1) L_[m][jj] += __shfl_xor(L_[m][jj], mk);
  if (l15 == 0){
#pragma unroll
    for (int m = 0; m < 2; ++m)
#pragma unroll
      for (int jj = 0; jj < 4; ++jj) redf[256 + wave * 32 + m * 16 + (grp << 2) + jj] = L_[m][jj];
  }
  __syncthreads();
  if (wave == 0 && l15 == 0){
#pragma unroll
    for (int m = 0; m < 2; ++m)
#pragma unroll
      for (int jj = 0; jj < 4; ++jj){
        int row = m * 16 + (grp << 2) + jj;
        float sum = 0.f;
#pragma unroll
        for (int w = 0; w < 8; ++w) sum += redf[256 + w * 32 + row];
        redf[512 + row] = 1.0f / (sum + 1e-20f);
      }
  }

  // ---- Phase D: O = P x V. Wave w owns t-columns [w*64 parts]; Pt per-wave private (gS overlay).
  char* ptW = smem + G_OFF + wave * 8192;   // [32 q][128 tl] u16, 256B rows, swizzled
#pragma unroll
  for (int s = 0; s < 2; ++s)
#pragma unroll
    for (int m = 0; m < 2; ++m)
#pragma unroll
      for (int c4 = 0; c4 < 4; ++c4)
#pragma unroll
        for (int jj = 0; jj < 4; ++jj){
          int q = m * 16 + (grp << 2) + jj;
          int tl = s * 64 + c4 * 16 + l15;
          *(u16*)(ptW + q * 256 + ((tl * 2) ^ ((q & 7) << 4))) = f2b(p[s][m][c4][jj]);
        }
  // stage VT seg0: rows d (64) x 512 t, 1024B rows, XOR (d&31)<<4
#pragma unroll
  for (int i = 0; i < 8; ++i){ int c = tid + i * 512, d = c >> 6, tc = c & 63;
    stv[i] = *(const us8*)(VTg + ((size_t)n * 64 + d) * 1024 + tc * 8); }
  __syncthreads();                 // all waves past softmax; Pt writes ordered below
#pragma unroll
  for (int i = 0; i < 8; ++i){ int c = tid + i * 512, d = c >> 6, tc = c & 63;
    *(us8*)(kvS + d * 1024 + ((tc * 16) ^ ((d & 31) << 4))) = stv[i]; }
#pragma unroll
  for (int i = 0; i < 8; ++i){ int c = tid + i * 512, d = c >> 6, tc = c & 63;
    stv[i] = *(const us8*)(VTg + ((size_t)n * 64 + d) * 1024 + 512 + tc * 8); }
  __syncthreads();

  f32x4 Oacc[2][4] = {};
#pragma unroll
  for (int s = 0; s < 2; ++s){
#pragma unroll
    for (int kk = 0; kk < 2; ++kk){
      short8 pa[2];
#pragma unroll
      for (int m = 0; m < 2; ++m)
        pa[m] = *(const short8*)(ptW + (m * 16 + l15) * 256 + ((s * 128 + kk * 64 + (grp << 4)) ^ ((l15 & 7) << 4)));
#pragma unroll
      for (int dt = 0; dt < 4; ++dt){
        int dr = dt * 16 + l15;
        short8 vb = *(const short8*)(kvS + dr * 1024 + ((wave * 128 + kk * 64 + (grp << 4)) ^ ((dr & 31) << 4)));
#pragma unroll
        for (int m = 0; m < 2; ++m)
          Oacc[m][dt] = __builtin_amdgcn_mfma_f32_16x16x32_bf16(pa[m], vb, Oacc[m][dt], 0, 0, 0);
      }
    }
    if (s == 0){
      __syncthreads();
#pragma unroll
      for (int i = 0; i < 8; ++i){ int c = tid + i * 512, d = c >> 6, tc = c & 63;
        *(us8*)(kvS + d * 1024 + ((tc * 16) ^ ((d & 31) << 4))) = stv[i]; }
      __syncthreads();
    }
  }

  // cross-wave reduce of partial O (8 x [32 q][64 d] f32 in kvS region)
  __syncthreads();
  float* par = (float*)kvS;
#pragma unroll
  for (int m = 0; m < 2; ++m)
#pragma unroll
    for (int dt = 0; dt < 4; ++dt)
#pragma unroll
      for (int jj = 0; jj < 4; ++jj)
        par[wave * 2048 + (m * 16 + (grp << 2) + jj) * 64 + dt * 16 + l15] = Oacc[m][dt][jj];
  __syncthreads();
  {
    f32x4 v = {0.f, 0.f, 0.f, 0.f};
#pragma unroll
    for (int w = 0; w < 8; ++w) v += *(const f32x4*)(par + w * 2048 + tid * 4);
    int q = tid >> 4, d4 = (tid & 15) * 4;
    float il = redf[512 + q];
    us4 pk;
#pragma unroll
    for (int e = 0; e < 4; ++e) pk[e] = f2b(v[e] * il);
    *(us4*)(ctx + ((size_t)(q0 + q) * 8 + bat) * 1024 + head * 64 + d4) = pk;
  }
}

// ---------------- launch ----------------
extern "C" void kernel_launch(void* const* d_in, const int* in_sizes, int n_in,
                              void* d_out, int out_size, void* d_ws, size_t ws_size,
                              hipStream_t stream){
  const float* x   = (const float*)d_in[0];
  const float* pos = (const float*)d_in[1];
  const float* Wi  = (const float*)d_in[2];
  const float* bi  = (const float*)d_in[3];
  const float* Wp  = (const float*)d_in[4];
  const float* bp  = (const float*)d_in[5];
  const float* Wo  = (const float*)d_in[6];
  const float* bo  = (const float*)d_in[7];
  const float* r_i = (const float*)d_in[8];
  const float* s_i = (const float*)d_in[9];
  const float* r_p = (const float*)d_in[10];
  const float* s_p = (const float*)d_in[11];
  const float* rwb = (const float*)d_in[12];
  const float* rrb = (const float*)d_in[13];

  const size_t MB = 1024 * 1024;
  u16* qkv = (u16*)((char*)d_ws);              // 48 MiB (bf16)
  u16* rk  = (u16*)((char*)d_ws + 48 * MB);    // 16 MiB (bf16); ws total 64 MiB
  // d_out (33.55 MB) scratch: VT bf16 16.78 MB at [0], ctx bf16 16.78 MB at [16.78MB]
  u16* VTg  = (u16*)d_out;
  u16* ctxg = (u16*)((char*)d_out + 16777216);

  k_gemm<true,  true,  false, false, false><<<dim3(24, 64), 256, 0, stream>>>(x,   Wi, r_i, s_i, bi, qkv, N3_);
  k_gemm<true,  true,  true,  false, false><<<dim3(8, 64),  256, 0, stream>>>(pos, Wp, r_p, s_p, bp, rk, 1024);
  k_vt<<<dim3(16, 128), 256, 0, stream>>>(qkv, VTg);
  k_attn<<<dim3(128, 32), 512, 0, stream>>>(qkv, rk, VTg, rwb, rrb, ctxg);
  hipMemcpyAsync(qkv, ctxg, (size_t)out_size * sizeof(u16), hipMemcpyDeviceToDevice, stream);
  k_gemm<false, false, false, true, true><<<dim3(8, 64), 256, 0, stream>>>(qkv, Wo, nullptr, nullptr, bo, (float*)d_out, 1024);
}